// Round 2
// baseline (6595.775 us; speedup 1.0000x reference)
//
#include <hip/hip_runtime.h>
#include <hip/hip_bf16.h>
#include <math.h>

// ---- problem constants ----
#define B_SZ 4
#define STXT 32
#define SIMG 224
#define LSEQ 256          // STXT + SIMG
#define IMGM 2048
#define PP 49             // SP*SP
#define HID 768
#define INTER 1536
#define NH 24
#define HD 64
#define DST 64
#define KCONV 4
#define NBLOCKS 4
#define OUT_D 32
#define INPUT_DIM 37632   // HID*PP
#define CONV_DIM 1664     // INTER + 2*DST
#define PROJ_D 3224       // INTER + CONV_DIM + NH
#define CONV_ROWS 896     // B_SZ * SIMG
#define EPSF 1e-5f

__device__ __forceinline__ float pe_val(int pos, int d) {
  int j = d >> 1;
  float div = expf((float)(2 * j) * (-9.210340371976184f / 768.f)); // -ln(10000)/768
  float arg = (float)pos * div;
  return (d & 1) ? cosf(arg) : sinf(arg);
}

__device__ __forceinline__ float silu_f(float v) { return v / (1.f + expf(-v)); }

// block = 256 threads (4 waves). Returns total to ALL threads.
__device__ __forceinline__ float blk_reduce(float v, float* red) {
#pragma unroll
  for (int off = 32; off > 0; off >>= 1) v += __shfl_down(v, off);
  int w = threadIdx.x >> 6;
  __syncthreads();
  if ((threadIdx.x & 63) == 0) red[w] = v;
  __syncthreads();
  return red[0] + red[1] + red[2] + red[3];
}

// ---------------- Stage 1: conv3d einsum (chunk of rows)
// out[local_row, d*49+p] = bias[d] + sum_c W[d,c] X[row0+local_row, c, p]
__global__ __launch_bounds__(256) void k_conv3d(const float* __restrict__ img,
                                                const float* __restrict__ W,
                                                const float* __restrict__ bias,
                                                float* __restrict__ out,
                                                int row0) {
  __shared__ float Ws[32][68];  // [kk][d]
  __shared__ float Xs[32][64];  // [kk][p], p padded 49->64 with zeros
  const int tid = threadIdx.x;
  const int tx = tid & 15, ty = tid >> 4;
  const int d0 = blockIdx.x * 64;
  const int lrow = blockIdx.y;
  const float* X = img + (size_t)(row0 + lrow) * (IMGM * PP);
  float acc[4][4] = {};
  for (int k0 = 0; k0 < IMGM; k0 += 32) {
#pragma unroll
    for (int i = 0; i < 8; ++i) {
      int idx = tid + i * 256;            // 0..2047
      int dd = idx >> 5, kk = idx & 31;
      Ws[kk][dd] = W[(size_t)(d0 + dd) * IMGM + (k0 + kk)];
    }
#pragma unroll
    for (int i = 0; i < 8; ++i) {
      int idx = tid + i * 256;
      int kk = idx >> 6, p = idx & 63;
      Xs[kk][p] = (p < PP) ? X[(size_t)(k0 + kk) * PP + p] : 0.f;
    }
    __syncthreads();
#pragma unroll
    for (int cc = 0; cc < 32; ++cc) {
      float4 a4 = *(const float4*)&Ws[cc][ty * 4];
      float4 b4 = *(const float4*)&Xs[cc][tx * 4];
      float av[4] = {a4.x, a4.y, a4.z, a4.w};
      float bv[4] = {b4.x, b4.y, b4.z, b4.w};
#pragma unroll
      for (int i = 0; i < 4; ++i)
#pragma unroll
        for (int j = 0; j < 4; ++j) acc[i][j] = fmaf(av[i], bv[j], acc[i][j]);
    }
    __syncthreads();
  }
#pragma unroll
  for (int i = 0; i < 4; ++i) {
    int dd = d0 + ty * 4 + i;
    float bv = bias[dd];
#pragma unroll
    for (int j = 0; j < 4; ++j) {
      int p = tx * 4 + j;
      if (p < PP) out[(size_t)lrow * INPUT_DIM + dd * PP + p] = acc[i][j] + bv;
    }
  }
}

// ---------------- Stage 2: LayerNorm stats over 37632 per local row; stats stored at global row
__global__ __launch_bounds__(256) void k_ln_stats(const float* __restrict__ x,
                                                  float* __restrict__ mean,
                                                  float* __restrict__ rstd,
                                                  int row0) {
  __shared__ float red[4];
  int lrow = blockIdx.x;
  const float* xr = x + (size_t)lrow * INPUT_DIM;
  float s = 0.f, s2 = 0.f;
  for (int c = threadIdx.x; c < INPUT_DIM; c += 256) { float v = xr[c]; s += v; s2 += v * v; }
  float ts = blk_reduce(s, red);
  float ts2 = blk_reduce(s2, red);
  if (threadIdx.x == 0) {
    float m = ts / (float)INPUT_DIM;
    float var = ts2 / (float)INPUT_DIM - m * m;
    mean[row0 + lrow] = m;
    rstd[row0 + lrow] = 1.f / sqrtf(var + EPSF);
  }
}

// ---------------- Stage 3a: init image rows of h with img_b + PE
__global__ __launch_bounds__(256) void k_hinit(const float* __restrict__ img_b,
                                               float* __restrict__ h) {
  int idx = blockIdx.x * 256 + threadIdx.x;
  if (idx >= B_SZ * SIMG * HID) return;
  int d = idx % HID;
  int r = idx / HID;            // b*224+s
  int s = r % SIMG, b = r / SIMG;
  h[((size_t)(b * LSEQ + STXT + s)) * HID + d] = img_b[d] + pe_val(s, d);
}

// ---------------- Stage 3b: instruction path: LN -> @ins_w + ins_b + PE -> h rows t<32
__global__ __launch_bounds__(256) void k_ins(const float* __restrict__ ins,
                                             const float* __restrict__ g,
                                             const float* __restrict__ bln,
                                             const float* __restrict__ W,
                                             const float* __restrict__ bias,
                                             float* __restrict__ h) {
  __shared__ float xs[HID];
  __shared__ float red[4];
  int row = blockIdx.x;               // 0..127 : b = row>>5, t = row&31
  const float* x = ins + (size_t)row * HID;
  float s = 0.f, s2 = 0.f;
  for (int c = threadIdx.x; c < HID; c += 256) { float v = x[c]; s += v; s2 += v * v; }
  float ts = blk_reduce(s, red);
  float ts2 = blk_reduce(s2, red);
  float m = ts / (float)HID;
  float var = ts2 / (float)HID - m * m;
  float r = 1.f / sqrtf(var + EPSF);
  for (int c = threadIdx.x; c < HID; c += 256) xs[c] = (x[c] - m) * r * g[c] + bln[c];
  __syncthreads();
  int b = row >> 5, t = row & 31;
  for (int dd = threadIdx.x; dd < HID; dd += 256) {
    float acc = 0.f;
    for (int c = 0; c < HID; ++c) acc = fmaf(xs[c], W[(size_t)c * HID + dd], acc);
    h[((size_t)(b * LSEQ + t)) * HID + dd] = acc + bias[dd] + pe_val(t, dd);
  }
}

// ---------------- Stage 4: img GEMM  h[b,32+s,:] += LN(conv_chunk) @ img_w  (split-K=8, atomic)
__global__ __launch_bounds__(256) void k_img_gemm(const float* __restrict__ conv_out,
                                                  const float* __restrict__ mean,
                                                  const float* __restrict__ rstd,
                                                  const float* __restrict__ g,
                                                  const float* __restrict__ bln,
                                                  const float* __restrict__ W,
                                                  float* __restrict__ h,
                                                  int row0) {
  __shared__ float As[32][68];
  __shared__ float Bs[32][68];
  const int tid = threadIdx.x;
  const int tx = tid & 15, ty = tid >> 4;
  const int n0 = blockIdx.x * 64;
  const int m0 = blockIdx.y * 64;            // local to chunk
  const int kbeg = blockIdx.z * (INPUT_DIM / 8);
  float acc[4][4] = {};
  for (int k0 = kbeg; k0 < kbeg + INPUT_DIM / 8; k0 += 32) {
#pragma unroll
    for (int i = 0; i < 8; ++i) {
      int idx = tid + i * 256;
      int mm = idx >> 5, kk = idx & 31;
      int lrow = m0 + mm, grow = row0 + lrow, gk = k0 + kk;
      float v = conv_out[(size_t)lrow * INPUT_DIM + gk];
      As[kk][mm] = (v - mean[grow]) * rstd[grow] * g[gk] + bln[gk];
    }
#pragma unroll
    for (int i = 0; i < 8; ++i) {
      int idx = tid + i * 256;
      int kk = idx >> 6, n = idx & 63;
      Bs[kk][n] = W[(size_t)(k0 + kk) * HID + (n0 + n)];
    }
    __syncthreads();
#pragma unroll
    for (int cc = 0; cc < 32; ++cc) {
      float4 a4 = *(const float4*)&As[cc][ty * 4];
      float4 b4 = *(const float4*)&Bs[cc][tx * 4];
      float av[4] = {a4.x, a4.y, a4.z, a4.w};
      float bv[4] = {b4.x, b4.y, b4.z, b4.w};
#pragma unroll
      for (int i = 0; i < 4; ++i)
#pragma unroll
        for (int j = 0; j < 4; ++j) acc[i][j] = fmaf(av[i], bv[j], acc[i][j]);
    }
    __syncthreads();
  }
#pragma unroll
  for (int i = 0; i < 4; ++i) {
    int grow = row0 + m0 + ty * 4 + i;
    int b = grow / SIMG, s = grow % SIMG;
    float* hr = h + ((size_t)(b * LSEQ + STXT + s)) * HID + n0 + tx * 4;
#pragma unroll
    for (int j = 0; j < 4; ++j) atomicAdd(hr + j, acc[i][j]);
  }
}

// ---------------- generic 64x64 fp32 GEMM: C[M,N] (+)= A[M,K] @ B[K,N]; K % 32 == 0
template <bool ACCUM>
__global__ __launch_bounds__(256) void k_gemm64(const float* __restrict__ A,
                                                const float* __restrict__ B,
                                                float* __restrict__ C,
                                                int M, int N, int K) {
  __shared__ float As[32][68];
  __shared__ float Bs[32][68];
  const int tid = threadIdx.x;
  const int tx = tid & 15, ty = tid >> 4;
  const int n0 = blockIdx.x * 64;
  const int m0 = blockIdx.y * 64;
  float acc[4][4] = {};
  for (int k0 = 0; k0 < K; k0 += 32) {
#pragma unroll
    for (int i = 0; i < 8; ++i) {
      int idx = tid + i * 256;
      int mm = idx >> 5, kk = idx & 31;
      int gm = m0 + mm;
      As[kk][mm] = (gm < M) ? A[(size_t)gm * K + (k0 + kk)] : 0.f;
    }
#pragma unroll
    for (int i = 0; i < 8; ++i) {
      int idx = tid + i * 256;
      int kk = idx >> 6, n = idx & 63;
      int gn = n0 + n;
      Bs[kk][n] = (gn < N) ? B[(size_t)(k0 + kk) * N + gn] : 0.f;
    }
    __syncthreads();
#pragma unroll
    for (int cc = 0; cc < 32; ++cc) {
      float4 a4 = *(const float4*)&As[cc][ty * 4];
      float4 b4 = *(const float4*)&Bs[cc][tx * 4];
      float av[4] = {a4.x, a4.y, a4.z, a4.w};
      float bv[4] = {b4.x, b4.y, b4.z, b4.w};
#pragma unroll
      for (int i = 0; i < 4; ++i)
#pragma unroll
        for (int j = 0; j < 4; ++j) acc[i][j] = fmaf(av[i], bv[j], acc[i][j]);
    }
    __syncthreads();
  }
#pragma unroll
  for (int i = 0; i < 4; ++i) {
    int gm = m0 + ty * 4 + i;
    if (gm >= M) continue;
#pragma unroll
    for (int j = 0; j < 4; ++j) {
      int gn = n0 + tx * 4 + j;
      if (gn < N) {
        size_t o = (size_t)gm * N + gn;
        if (ACCUM) C[o] += acc[i][j]; else C[o] = acc[i][j];
      }
    }
  }
}

// ---------------- per-layer: rmsnorm * w * mask
__global__ __launch_bounds__(256) void k_rmsnorm_mask(const float* __restrict__ h,
                                                      const float* __restrict__ w,
                                                      const int* __restrict__ mask,
                                                      float* __restrict__ hn) {
  __shared__ float red[4];
  int row = blockIdx.x;            // b*256+t
  const float* xr = h + (size_t)row * HID;
  float s2 = 0.f;
  for (int c = threadIdx.x; c < HID; c += 256) { float v = xr[c]; s2 += v * v; }
  float ts2 = blk_reduce(s2, red);
  float r = 1.f / sqrtf(ts2 / (float)HID + EPSF);
  float mf = (mask[row] != 0) ? 1.f : 0.f;
  for (int c = threadIdx.x; c < HID; c += 256)
    hn[(size_t)row * HID + c] = xr[c] * r * w[c] * mf;
}

// ---------------- causal depthwise conv (K=4) + silu + mask
__global__ __launch_bounds__(256) void k_dconv(const float* __restrict__ proj,
                                               const float* __restrict__ cw,
                                               const float* __restrict__ cb,
                                               const int* __restrict__ mask,
                                               float* __restrict__ xbc) {
  int ch = blockIdx.x * 256 + threadIdx.x;
  if (ch >= CONV_DIM) return;
  int t = blockIdx.y, b = blockIdx.z;
  float acc = cb[ch];
#pragma unroll
  for (int k = 0; k < KCONV; ++k) {
    int tt = t + k - (KCONV - 1);
    if (tt >= 0)
      acc = fmaf(cw[ch * KCONV + k], proj[((size_t)(b * LSEQ + tt)) * PROJ_D + INTER + ch], acc);
  }
  float mf = (mask[b * LSEQ + t] != 0) ? 1.f : 0.f;
  xbc[((size_t)(b * LSEQ + t)) * CONV_DIM + ch] = silu_f(acc) * mf;
}

// ---------------- dt = softplus(dt_raw + bias); dA = exp(dt * -exp(A_log))
__global__ __launch_bounds__(256) void k_dt(const float* __restrict__ proj,
                                            const float* __restrict__ dtb,
                                            const float* __restrict__ alog,
                                            float* __restrict__ dt,
                                            float* __restrict__ dA) {
  int idx = blockIdx.x * 256 + threadIdx.x;
  if (idx >= B_SZ * LSEQ * NH) return;
  int hh = idx % NH;
  int row = idx / NH;
  float v = proj[(size_t)row * PROJ_D + INTER + CONV_DIM + hh] + dtb[hh];
  float sp = fmaxf(v, 0.f) + log1pf(expf(-fabsf(v)));
  float A = -expf(alog[hh]);
  dt[idx] = sp;
  dA[idx] = expf(sp * A);
}

// ---------------- sequential selective scan: block = (h, b); thread owns (p, 16 n-states)
__global__ __launch_bounds__(256) void k_scan(const float* __restrict__ xbc,
                                              const float* __restrict__ dtb,
                                              const float* __restrict__ dAb,
                                              const float* __restrict__ Dp,
                                              float* __restrict__ yfull) {
  const int h = blockIdx.x, b = blockIdx.y;
  const int tid = threadIdx.x;
  const int p = tid >> 2, ng = tid & 3;       // p 0..63, n-block of 16
  float st[16];
#pragma unroll
  for (int j = 0; j < 16; ++j) st[j] = 0.f;
  const float Dh = Dp[h];
  for (int t = 0; t < LSEQ; ++t) {
    const size_t rb = (size_t)(b * LSEQ + t);
    const float dAv = dAb[rb * NH + h];
    const float dtv = dtb[rb * NH + h];
    const float* xr = xbc + rb * CONV_DIM;
    const float xv = xr[h * HD + p];
    const float4* Bp = (const float4*)(xr + INTER + ng * 16);
    const float4* Cp = (const float4*)(xr + INTER + DST + ng * 16);
    float coeff = dtv * xv;
    float ps = 0.f;
#pragma unroll
    for (int q = 0; q < 4; ++q) {
      float4 Bv = Bp[q];
      float4 Cv = Cp[q];
      st[q * 4 + 0] = fmaf(st[q * 4 + 0], dAv, coeff * Bv.x); ps = fmaf(st[q * 4 + 0], Cv.x, ps);
      st[q * 4 + 1] = fmaf(st[q * 4 + 1], dAv, coeff * Bv.y); ps = fmaf(st[q * 4 + 1], Cv.y, ps);
      st[q * 4 + 2] = fmaf(st[q * 4 + 2], dAv, coeff * Bv.z); ps = fmaf(st[q * 4 + 2], Cv.z, ps);
      st[q * 4 + 3] = fmaf(st[q * 4 + 3], dAv, coeff * Bv.w); ps = fmaf(st[q * 4 + 3], Cv.w, ps);
    }
    ps += __shfl_xor(ps, 1);
    ps += __shfl_xor(ps, 2);
    if (ng == 0) yfull[rb * INTER + h * HD + p] = ps + Dh * xv;
  }
}

// ---------------- gated rmsnorm: yg = rmsnorm(yfull * silu(z), gnorm_w)
__global__ __launch_bounds__(256) void k_gate(const float* __restrict__ yfull,
                                              const float* __restrict__ proj,
                                              const float* __restrict__ gw,
                                              float* __restrict__ yg) {
  __shared__ float vs[INTER];
  __shared__ float red[4];
  int row = blockIdx.x;
  float s2 = 0.f;
  for (int c = threadIdx.x; c < INTER; c += 256) {
    float z = proj[(size_t)row * PROJ_D + c];
    float v = yfull[(size_t)row * INTER + c] * silu_f(z);
    vs[c] = v;
    s2 += v * v;
  }
  float ts2 = blk_reduce(s2, red);
  float r = 1.f / sqrtf(ts2 / (float)INTER + EPSF);
  __syncthreads();
  for (int c = threadIdx.x; c < INTER; c += 256)
    yg[(size_t)row * INTER + c] = vs[c] * r * gw[c];
}

// ---------------- final: rmsnorm(h) @ head_w + head_b, rows t>=32
__global__ __launch_bounds__(256) void k_head(const float* __restrict__ h,
                                              const float* __restrict__ nw,
                                              const float* __restrict__ W,
                                              const float* __restrict__ bias,
                                              float* __restrict__ out) {
  __shared__ float xs[HID];
  __shared__ float red[4];
  __shared__ float red2[8][OUT_D];
  int s = blockIdx.x, b = blockIdx.y;
  int row = b * LSEQ + STXT + s;
  const float* xr = h + (size_t)row * HID;
  float s2 = 0.f;
  for (int c = threadIdx.x; c < HID; c += 256) { float v = xr[c]; s2 += v * v; }
  float ts2 = blk_reduce(s2, red);
  float r = 1.f / sqrtf(ts2 / (float)HID + EPSF);
  for (int c = threadIdx.x; c < HID; c += 256) xs[c] = xr[c] * r * nw[c];
  __syncthreads();
  int d = threadIdx.x & 31, chunk = threadIdx.x >> 5;   // 8 chunks x 96
  float acc = 0.f;
  for (int c = chunk * 96; c < chunk * 96 + 96; ++c) acc = fmaf(xs[c], W[(size_t)c * OUT_D + d], acc);
  red2[chunk][d] = acc;
  __syncthreads();
  if (threadIdx.x < OUT_D) {
    float tot = 0.f;
#pragma unroll
    for (int q = 0; q < 8; ++q) tot += red2[q][threadIdx.x];
    out[((size_t)(b * SIMG + s)) * OUT_D + threadIdx.x] = tot + bias[threadIdx.x];
  }
}

extern "C" void kernel_launch(void* const* d_in, const int* in_sizes, int n_in,
                              void* d_out, int out_size, void* d_ws, size_t ws_size,
                              hipStream_t stream) {
  const float* image_embs       = (const float*)d_in[0];
  const float* instruction_embs = (const float*)d_in[1];
  const int*   pad_mask         = (const int*)d_in[2];
  const float* conv3d_w         = (const float*)d_in[3];
  const float* conv3d_b         = (const float*)d_in[4];
  const float* ln_img_g         = (const float*)d_in[5];
  const float* ln_img_b         = (const float*)d_in[6];
  const float* ln_ins_g         = (const float*)d_in[7];
  const float* ln_ins_b         = (const float*)d_in[8];
  const float* ins_w            = (const float*)d_in[9];
  const float* ins_b            = (const float*)d_in[10];
  const float* img_w            = (const float*)d_in[11];
  const float* img_b            = (const float*)d_in[12];
  const float* head_w           = (const float*)d_in[13];
  const float* head_b           = (const float*)d_in[14];
  const float* in_proj_w        = (const float*)d_in[15];
  const float* norm_w           = (const float*)d_in[16];
  const float* conv_w           = (const float*)d_in[17];
  const float* conv_b           = (const float*)d_in[18];
  const float* dt_bias          = (const float*)d_in[19];
  const float* A_log            = (const float*)d_in[20];
  const float* Dp               = (const float*)d_in[21];
  const float* gnorm_w          = (const float*)d_in[22];
  const float* out_proj_w       = (const float*)d_in[23];
  const float* normf_w          = (const float*)d_in[24];

  // ---- workspace layout (floats) ----
  // fixed region: h (1024x768) + stats (2x896)
  // scratch region (aliased): stage-A conv chunk buffer, then mamba-loop buffers.
  float* ws      = (float*)d_ws;
  float* h       = ws;                         // 786432
  float* mean    = h + 1024 * HID;             // 896
  float* rstd    = mean + CONV_ROWS;           // 896
  float* scratch = rstd + CONV_ROWS;

  const size_t ws_floats   = ws_size / sizeof(float);
  const size_t fixed       = (size_t)(scratch - ws);
  const size_t avail       = (ws_floats > fixed) ? (ws_floats - fixed) : 0;

  // stage-A chunk: largest multiple-of-64 row count whose conv buffer fits.
  int chunkM = (int)(avail / INPUT_DIM);
  chunkM = (chunkM / 64) * 64;
  if (chunkM > CONV_ROWS) chunkM = CONV_ROWS;
  if (chunkM < 64) chunkM = 64;   // minimum; below this nothing fits anyway

  float* conv_buf = scratch;                   // chunkM * 37632 floats

  // mamba-loop scratch aliases the (dead) conv buffer region: ~9.0M floats
  float* hn    = scratch;                      // 786432
  float* proj  = hn + 1024 * HID;              // 3301376
  float* xbc   = proj + 1024 * PROJ_D;         // 1703936
  float* dtB   = xbc + 1024 * CONV_DIM;        // 24576
  float* dAB   = dtB + 1024 * NH;              // 24576
  float* yfull = dAB + 1024 * NH;              // 1572864
  float* yg    = yfull + 1024 * INTER;         // 1572864

  // ---- stage A: vision + instruction embedding ----
  k_hinit<<<(B_SZ * SIMG * HID + 255) / 256, 256, 0, stream>>>(img_b, h);
  k_ins<<<128, 256, 0, stream>>>(instruction_embs, ln_ins_g, ln_ins_b, ins_w, ins_b, h);

  for (int row0 = 0; row0 < CONV_ROWS; row0 += chunkM) {
    int m = CONV_ROWS - row0; if (m > chunkM) m = chunkM;   // always multiple of 64
    k_conv3d<<<dim3(12, m), 256, 0, stream>>>(image_embs, conv3d_w, conv3d_b, conv_buf, row0);
    k_ln_stats<<<m, 256, 0, stream>>>(conv_buf, mean, rstd, row0);
    k_img_gemm<<<dim3(12, m / 64, 8), 256, 0, stream>>>(conv_buf, mean, rstd, ln_img_g,
                                                        ln_img_b, img_w, h, row0);
  }

  // ---- stage B: 4 mamba2 blocks ----
  for (int l = 0; l < NBLOCKS; ++l) {
    k_rmsnorm_mask<<<1024, 256, 0, stream>>>(h, norm_w + l * HID, pad_mask, hn);
    k_gemm64<false><<<dim3((PROJ_D + 63) / 64, 16), 256, 0, stream>>>(
        hn, in_proj_w + (size_t)l * HID * PROJ_D, proj, 1024, PROJ_D, HID);
    k_dconv<<<dim3((CONV_DIM + 255) / 256, LSEQ, B_SZ), 256, 0, stream>>>(
        proj, conv_w + l * CONV_DIM * KCONV, conv_b + l * CONV_DIM, pad_mask, xbc);
    k_dt<<<(B_SZ * LSEQ * NH + 255) / 256, 256, 0, stream>>>(
        proj, dt_bias + l * NH, A_log + l * NH, dtB, dAB);
    k_scan<<<dim3(NH, B_SZ), 256, 0, stream>>>(xbc, dtB, dAB, Dp + l * NH, yfull);
    k_gate<<<1024, 256, 0, stream>>>(yfull, proj, gnorm_w + l * INTER, yg);
    k_gemm64<true><<<dim3(HID / 64, 16), 256, 0, stream>>>(
        yg, out_proj_w + (size_t)l * INTER * HID, h, 1024, HID, INTER);
  }

  // ---- stage C: head ----
  k_head<<<dim3(SIMG, B_SZ), 256, 0, stream>>>(h, normf_w, head_w, head_b, (float*)d_out);
}

// Round 4
// 3795.940 us; speedup vs baseline: 1.7376x; 1.7376x over previous
//
#include <hip/hip_runtime.h>
#include <hip/hip_bf16.h>
#include <math.h>

// ---- problem constants ----
#define B_SZ 4
#define STXT 32
#define SIMG 224
#define LSEQ 256          // STXT + SIMG
#define IMGM 2048
#define PP 49             // SP*SP
#define HID 768
#define INTER 1536
#define NH 24
#define HD 64
#define DST 64
#define KCONV 4
#define NBLOCKS 4
#define OUT_D 32
#define INPUT_DIM 37632   // HID*PP
#define CONV_DIM 1664     // INTER + 2*DST
#define PROJ_D 3224       // INTER + CONV_DIM + NH
#define CONV_ROWS 896     // B_SZ * SIMG
#define EPSF 1e-5f

typedef __bf16 bf16_t;
typedef __attribute__((ext_vector_type(8))) __bf16 bf16x8;
typedef __attribute__((ext_vector_type(4))) float f32x4;

#define LDS_STRIDE 72     // bf16 elems per LDS tile row (144 B, 16B-aligned)

__device__ __forceinline__ float pe_val(int pos, int d) {
  int j = d >> 1;
  float div = expf((float)(2 * j) * (-9.210340371976184f / 768.f)); // -ln(10000)/768
  float arg = (float)pos * div;
  return (d & 1) ? cosf(arg) : sinf(arg);
}

__device__ __forceinline__ float silu_f(float v) { return v / (1.f + expf(-v)); }

// block = 256 threads (4 waves). Returns total to ALL threads.
__device__ __forceinline__ float blk_reduce(float v, float* red) {
#pragma unroll
  for (int off = 32; off > 0; off >>= 1) v += __shfl_down(v, off);
  int w = threadIdx.x >> 6;
  __syncthreads();
  if ((threadIdx.x & 63) == 0) red[w] = v;
  __syncthreads();
  return red[0] + red[1] + red[2] + red[3];
}

// MFMA 64x64 tile core: 4 waves, wave w covers rows [w*16, w*16+16).
// As: [64][LDS_STRIDE] bf16, A[row][k] for k-tile of 64.
// Bs: [64][LDS_STRIDE] bf16, B^T[col][k].
// acc[nf] covers cols [nf*16, nf*16+16).
__device__ __forceinline__ void mfma_64tile(const bf16_t* As, const bf16_t* Bs,
                                            f32x4 acc[4], int w, int lr, int kq) {
#pragma unroll
  for (int ks = 0; ks < 2; ++ks) {
    bf16x8 a = *(const bf16x8*)(As + (w * 16 + lr) * LDS_STRIDE + ks * 32 + kq * 8);
#pragma unroll
    for (int nf = 0; nf < 4; ++nf) {
      bf16x8 b = *(const bf16x8*)(Bs + (nf * 16 + lr) * LDS_STRIDE + ks * 32 + kq * 8);
      acc[nf] = __builtin_amdgcn_mfma_f32_16x16x32_bf16(a, b, acc[nf], 0, 0, 0);
    }
  }
}

// ---------------- Stage 1: conv3d einsum (chunk of rows), bf16 MFMA
// out[lrow, d*49+p] = bias[d] + sum_c W[d,c] X[row0+lrow, c, p]
__global__ __launch_bounds__(256) void k_conv3d(const float* __restrict__ img,
                                                const float* __restrict__ W,
                                                const float* __restrict__ bias,
                                                float* __restrict__ out,
                                                int row0) {
  __shared__ __align__(16) bf16_t Ws[64 * LDS_STRIDE];
  __shared__ __align__(16) bf16_t Xs[64 * LDS_STRIDE];
  const int tid = threadIdx.x;
  const int lane = tid & 63, w = tid >> 6;
  const int lr = lane & 15, kq = lane >> 4;
  const int d0 = blockIdx.x * 64;
  const int lrow = blockIdx.y;
  const float* X = img + (size_t)(row0 + lrow) * (IMGM * PP);
  f32x4 acc[4] = {};
  for (int k0 = 0; k0 < IMGM; k0 += 64) {
    __syncthreads();
#pragma unroll
    for (int i = 0; i < 4; ++i) {
      int idx = tid + i * 256;              // 0..1023
      int dd = idx >> 4, kc = idx & 15;
      float4 v = *(const float4*)&W[(size_t)(d0 + dd) * IMGM + k0 + kc * 4];
      bf16_t* dst = &Ws[dd * LDS_STRIDE + kc * 4];
      dst[0] = (bf16_t)v.x; dst[1] = (bf16_t)v.y; dst[2] = (bf16_t)v.z; dst[3] = (bf16_t)v.w;
    }
#pragma unroll
    for (int i = 0; i < 16; ++i) {
      int idx = tid + i * 256;              // 0..4095
      int kk = idx >> 6, p = idx & 63;
      float v = (p < PP) ? X[(size_t)(k0 + kk) * PP + p] : 0.f;
      Xs[p * LDS_STRIDE + kk] = (bf16_t)v;  // transposed: [p][k]
    }
    __syncthreads();
    mfma_64tile(Ws, Xs, acc, w, lr, kq);
  }
  const size_t orow = (size_t)lrow * INPUT_DIM;
#pragma unroll
  for (int nf = 0; nf < 4; ++nf) {
    int p = nf * 16 + lr;
    if (p < PP) {
#pragma unroll
      for (int r = 0; r < 4; ++r) {
        int dd = d0 + w * 16 + kq * 4 + r;
        out[orow + (size_t)dd * PP + p] = acc[nf][r] + bias[dd];
      }
    }
  }
}

// ---------------- Stage 2: LayerNorm stats over 37632 per local row
__global__ __launch_bounds__(256) void k_ln_stats(const float* __restrict__ x,
                                                  float* __restrict__ mean,
                                                  float* __restrict__ rstd,
                                                  int row0) {
  __shared__ float red[4];
  int lrow = blockIdx.x;
  const float* xr = x + (size_t)lrow * INPUT_DIM;
  float s = 0.f, s2 = 0.f;
  for (int c = threadIdx.x; c < INPUT_DIM; c += 256) { float v = xr[c]; s += v; s2 += v * v; }
  float ts = blk_reduce(s, red);
  float ts2 = blk_reduce(s2, red);
  if (threadIdx.x == 0) {
    float m = ts / (float)INPUT_DIM;
    float var = ts2 / (float)INPUT_DIM - m * m;
    mean[row0 + lrow] = m;
    rstd[row0 + lrow] = 1.f / sqrtf(var + EPSF);
  }
}

// ---------------- Stage 3a: init image rows of h with img_b + PE
__global__ __launch_bounds__(256) void k_hinit(const float* __restrict__ img_b,
                                               float* __restrict__ h) {
  int idx = blockIdx.x * 256 + threadIdx.x;
  if (idx >= B_SZ * SIMG * HID) return;
  int d = idx % HID;
  int r = idx / HID;            // b*224+s
  int s = r % SIMG, b = r / SIMG;
  h[((size_t)(b * LSEQ + STXT + s)) * HID + d] = img_b[d] + pe_val(s, d);
}

// ---------------- Stage 3b: instruction path (small; fp32)
__global__ __launch_bounds__(256) void k_ins(const float* __restrict__ ins,
                                             const float* __restrict__ g,
                                             const float* __restrict__ bln,
                                             const float* __restrict__ W,
                                             const float* __restrict__ bias,
                                             float* __restrict__ h) {
  __shared__ float xs[HID];
  __shared__ float red[4];
  int row = blockIdx.x;               // 0..127 : b = row>>5, t = row&31
  const float* x = ins + (size_t)row * HID;
  float s = 0.f, s2 = 0.f;
  for (int c = threadIdx.x; c < HID; c += 256) { float v = x[c]; s += v; s2 += v * v; }
  float ts = blk_reduce(s, red);
  float ts2 = blk_reduce(s2, red);
  float m = ts / (float)HID;
  float var = ts2 / (float)HID - m * m;
  float r = 1.f / sqrtf(var + EPSF);
  for (int c = threadIdx.x; c < HID; c += 256) xs[c] = (x[c] - m) * r * g[c] + bln[c];
  __syncthreads();
  int b = row >> 5, t = row & 31;
  for (int dd = threadIdx.x; dd < HID; dd += 256) {
    float acc = 0.f;
    for (int c = 0; c < HID; ++c) acc = fmaf(xs[c], W[(size_t)c * HID + dd], acc);
    h[((size_t)(b * LSEQ + t)) * HID + dd] = acc + bias[dd] + pe_val(t, dd);
  }
}

// ---------------- Stage 4: img GEMM (bf16 MFMA, LN fused into A-staging, split-K=12)
__global__ __launch_bounds__(256) void k_img_gemm(const float* __restrict__ conv_out,
                                                  const float* __restrict__ mean,
                                                  const float* __restrict__ rstd,
                                                  const float* __restrict__ g,
                                                  const float* __restrict__ bln,
                                                  const float* __restrict__ W,
                                                  float* __restrict__ h,
                                                  int row0) {
  __shared__ __align__(16) bf16_t As[64 * LDS_STRIDE];
  __shared__ __align__(16) bf16_t Bs[64 * LDS_STRIDE];
  const int tid = threadIdx.x;
  const int lane = tid & 63, w = tid >> 6;
  const int lr = lane & 15, kq = lane >> 4;
  const int n0 = blockIdx.x * 64;
  const int m0 = blockIdx.y * 64;            // local to chunk
  const int kbeg = blockIdx.z * (INPUT_DIM / 12);   // 3136 per split, 49 k-tiles
  f32x4 acc[4] = {};
  for (int k0 = kbeg; k0 < kbeg + INPUT_DIM / 12; k0 += 64) {
    __syncthreads();
#pragma unroll
    for (int i = 0; i < 4; ++i) {
      int idx = tid + i * 256;
      int mm = idx >> 4, kc = idx & 15;
      int grow = row0 + m0 + mm;
      int gk = k0 + kc * 4;
      float4 v = *(const float4*)&conv_out[(size_t)(m0 + mm) * INPUT_DIM + gk];
      float4 gg = *(const float4*)&g[gk];
      float4 bb = *(const float4*)&bln[gk];
      float mu = mean[grow], rs = rstd[grow];
      bf16_t* dst = &As[mm * LDS_STRIDE + kc * 4];
      dst[0] = (bf16_t)((v.x - mu) * rs * gg.x + bb.x);
      dst[1] = (bf16_t)((v.y - mu) * rs * gg.y + bb.y);
      dst[2] = (bf16_t)((v.z - mu) * rs * gg.z + bb.z);
      dst[3] = (bf16_t)((v.w - mu) * rs * gg.w + bb.w);
    }
#pragma unroll
    for (int i = 0; i < 16; ++i) {
      int idx = tid + i * 256;
      int kk = idx >> 6, nn = idx & 63;
      float v = W[(size_t)(k0 + kk) * HID + (n0 + nn)];
      Bs[nn * LDS_STRIDE + kk] = (bf16_t)v;   // transposed: [n][k]
    }
    __syncthreads();
    mfma_64tile(As, Bs, acc, w, lr, kq);
  }
#pragma unroll
  for (int nf = 0; nf < 4; ++nf) {
    int n = n0 + nf * 16 + lr;
#pragma unroll
    for (int r = 0; r < 4; ++r) {
      int grow = row0 + m0 + w * 16 + kq * 4 + r;
      int b = grow / SIMG, s = grow % SIMG;
      atomicAdd(&h[((size_t)(b * LSEQ + STXT + s)) * HID + n], acc[nf][r]);
    }
  }
}

// ---------------- generic bf16-MFMA GEMM: C[M,N] (+)= A[M,K] @ B[K,N]
// M % 64 == 0 (grid covers exactly), K % 64 == 0, N arbitrary (guarded).
template <bool ACCUM>
__global__ __launch_bounds__(256) void k_gemm64(const float* __restrict__ A,
                                                const float* __restrict__ B,
                                                float* __restrict__ C,
                                                int N, int K) {
  __shared__ __align__(16) bf16_t As[64 * LDS_STRIDE];
  __shared__ __align__(16) bf16_t Bs[64 * LDS_STRIDE];
  const int tid = threadIdx.x;
  const int lane = tid & 63, w = tid >> 6;
  const int lr = lane & 15, kq = lane >> 4;
  const int n0 = blockIdx.x * 64;
  const int m0 = blockIdx.y * 64;
  f32x4 acc[4] = {};
  for (int k0 = 0; k0 < K; k0 += 64) {
    __syncthreads();
#pragma unroll
    for (int i = 0; i < 4; ++i) {
      int idx = tid + i * 256;
      int mm = idx >> 4, kc = idx & 15;
      float4 v = *(const float4*)&A[(size_t)(m0 + mm) * K + k0 + kc * 4];
      bf16_t* dst = &As[mm * LDS_STRIDE + kc * 4];
      dst[0] = (bf16_t)v.x; dst[1] = (bf16_t)v.y; dst[2] = (bf16_t)v.z; dst[3] = (bf16_t)v.w;
    }
#pragma unroll
    for (int i = 0; i < 16; ++i) {
      int idx = tid + i * 256;
      int kk = idx >> 6, nn = idx & 63;
      int gn = n0 + nn;
      float v = (gn < N) ? B[(size_t)(k0 + kk) * N + gn] : 0.f;
      Bs[nn * LDS_STRIDE + kk] = (bf16_t)v;
    }
    __syncthreads();
    mfma_64tile(As, Bs, acc, w, lr, kq);
  }
#pragma unroll
  for (int nf = 0; nf < 4; ++nf) {
    int col = n0 + nf * 16 + lr;
    if (col < N) {
#pragma unroll
      for (int r = 0; r < 4; ++r) {
        int row = m0 + w * 16 + kq * 4 + r;
        size_t o = (size_t)row * N + col;
        if (ACCUM) C[o] += acc[nf][r]; else C[o] = acc[nf][r];
      }
    }
  }
}

// ---------------- per-layer: rmsnorm * w * mask
__global__ __launch_bounds__(256) void k_rmsnorm_mask(const float* __restrict__ h,
                                                      const float* __restrict__ w,
                                                      const int* __restrict__ mask,
                                                      float* __restrict__ hn) {
  __shared__ float red[4];
  int row = blockIdx.x;            // b*256+t
  const float* xr = h + (size_t)row * HID;
  float s2 = 0.f;
  for (int c = threadIdx.x; c < HID; c += 256) { float v = xr[c]; s2 += v * v; }
  float ts2 = blk_reduce(s2, red);
  float r = 1.f / sqrtf(ts2 / (float)HID + EPSF);
  float mf = (mask[row] != 0) ? 1.f : 0.f;
  for (int c = threadIdx.x; c < HID; c += 256)
    hn[(size_t)row * HID + c] = xr[c] * r * w[c] * mf;
}

// ---------------- causal depthwise conv (K=4) + silu + mask
__global__ __launch_bounds__(256) void k_dconv(const float* __restrict__ proj,
                                               const float* __restrict__ cw,
                                               const float* __restrict__ cb,
                                               const int* __restrict__ mask,
                                               float* __restrict__ xbc) {
  int ch = blockIdx.x * 256 + threadIdx.x;
  if (ch >= CONV_DIM) return;
  int t = blockIdx.y, b = blockIdx.z;
  float acc = cb[ch];
#pragma unroll
  for (int k = 0; k < KCONV; ++k) {
    int tt = t + k - (KCONV - 1);
    if (tt >= 0)
      acc = fmaf(cw[ch * KCONV + k], proj[((size_t)(b * LSEQ + tt)) * PROJ_D + INTER + ch], acc);
  }
  float mf = (mask[b * LSEQ + t] != 0) ? 1.f : 0.f;
  xbc[((size_t)(b * LSEQ + t)) * CONV_DIM + ch] = silu_f(acc) * mf;
}

// ---------------- dt = softplus(dt_raw + bias); dA = exp(dt * -exp(A_log))
__global__ __launch_bounds__(256) void k_dt(const float* __restrict__ proj,
                                            const float* __restrict__ dtb,
                                            const float* __restrict__ alog,
                                            float* __restrict__ dt,
                                            float* __restrict__ dA) {
  int idx = blockIdx.x * 256 + threadIdx.x;
  if (idx >= B_SZ * LSEQ * NH) return;
  int hh = idx % NH;
  int row = idx / NH;
  float v = proj[(size_t)row * PROJ_D + INTER + CONV_DIM + hh] + dtb[hh];
  float sp = fmaxf(v, 0.f) + log1pf(expf(-fabsf(v)));
  float A = -expf(alog[hh]);
  dt[idx] = sp;
  dA[idx] = expf(sp * A);
}

// ---------------- sequential selective scan
__global__ __launch_bounds__(256) void k_scan(const float* __restrict__ xbc,
                                              const float* __restrict__ dtb,
                                              const float* __restrict__ dAb,
                                              const float* __restrict__ Dp,
                                              float* __restrict__ yfull) {
  const int h = blockIdx.x, b = blockIdx.y;
  const int tid = threadIdx.x;
  const int p = tid >> 2, ng = tid & 3;       // p 0..63, n-block of 16
  float st[16];
#pragma unroll
  for (int j = 0; j < 16; ++j) st[j] = 0.f;
  const float Dh = Dp[h];
  for (int t = 0; t < LSEQ; ++t) {
    const size_t rb = (size_t)(b * LSEQ + t);
    const float dAv = dAb[rb * NH + h];
    const float dtv = dtb[rb * NH + h];
    const float* xr = xbc + rb * CONV_DIM;
    const float xv = xr[h * HD + p];
    const float4* Bp = (const float4*)(xr + INTER + ng * 16);
    const float4* Cp = (const float4*)(xr + INTER + DST + ng * 16);
    float coeff = dtv * xv;
    float ps = 0.f;
#pragma unroll
    for (int q = 0; q < 4; ++q) {
      float4 Bv = Bp[q];
      float4 Cv = Cp[q];
      st[q * 4 + 0] = fmaf(st[q * 4 + 0], dAv, coeff * Bv.x); ps = fmaf(st[q * 4 + 0], Cv.x, ps);
      st[q * 4 + 1] = fmaf(st[q * 4 + 1], dAv, coeff * Bv.y); ps = fmaf(st[q * 4 + 1], Cv.y, ps);
      st[q * 4 + 2] = fmaf(st[q * 4 + 2], dAv, coeff * Bv.z); ps = fmaf(st[q * 4 + 2], Cv.z, ps);
      st[q * 4 + 3] = fmaf(st[q * 4 + 3], dAv, coeff * Bv.w); ps = fmaf(st[q * 4 + 3], Cv.w, ps);
    }
    ps += __shfl_xor(ps, 1);
    ps += __shfl_xor(ps, 2);
    if (ng == 0) yfull[rb * INTER + h * HD + p] = ps + Dh * xv;
  }
}

// ---------------- gated rmsnorm: yg = rmsnorm(yfull * silu(z), gnorm_w)
__global__ __launch_bounds__(256) void k_gate(const float* __restrict__ yfull,
                                              const float* __restrict__ proj,
                                              const float* __restrict__ gw,
                                              float* __restrict__ yg) {
  __shared__ float vs[INTER];
  __shared__ float red[4];
  int row = blockIdx.x;
  float s2 = 0.f;
  for (int c = threadIdx.x; c < INTER; c += 256) {
    float z = proj[(size_t)row * PROJ_D + c];
    float v = yfull[(size_t)row * INTER + c] * silu_f(z);
    vs[c] = v;
    s2 += v * v;
  }
  float ts2 = blk_reduce(s2, red);
  float r = 1.f / sqrtf(ts2 / (float)INTER + EPSF);
  __syncthreads();
  for (int c = threadIdx.x; c < INTER; c += 256)
    yg[(size_t)row * INTER + c] = vs[c] * r * gw[c];
}

// ---------------- final: rmsnorm(h) @ head_w + head_b, rows t>=32
__global__ __launch_bounds__(256) void k_head(const float* __restrict__ h,
                                              const float* __restrict__ nw,
                                              const float* __restrict__ W,
                                              const float* __restrict__ bias,
                                              float* __restrict__ out) {
  __shared__ float xs[HID];
  __shared__ float red[4];
  __shared__ float red2[8][OUT_D];
  int s = blockIdx.x, b = blockIdx.y;
  int row = b * LSEQ + STXT + s;
  const float* xr = h + (size_t)row * HID;
  float s2 = 0.f;
  for (int c = threadIdx.x; c < HID; c += 256) { float v = xr[c]; s2 += v * v; }
  float ts2 = blk_reduce(s2, red);
  float r = 1.f / sqrtf(ts2 / (float)HID + EPSF);
  for (int c = threadIdx.x; c < HID; c += 256) xs[c] = xr[c] * r * nw[c];
  __syncthreads();
  int d = threadIdx.x & 31, chunk = threadIdx.x >> 5;   // 8 chunks x 96
  float acc = 0.f;
  for (int c = chunk * 96; c < chunk * 96 + 96; ++c) acc = fmaf(xs[c], W[(size_t)c * OUT_D + d], acc);
  red2[chunk][d] = acc;
  __syncthreads();
  if (threadIdx.x < OUT_D) {
    float tot = 0.f;
#pragma unroll
    for (int q = 0; q < 8; ++q) tot += red2[q][threadIdx.x];
    out[((size_t)(b * SIMG + s)) * OUT_D + threadIdx.x] = tot + bias[threadIdx.x];
  }
}

extern "C" void kernel_launch(void* const* d_in, const int* in_sizes, int n_in,
                              void* d_out, int out_size, void* d_ws, size_t ws_size,
                              hipStream_t stream) {
  const float* image_embs       = (const float*)d_in[0];
  const float* instruction_embs = (const float*)d_in[1];
  const int*   pad_mask         = (const int*)d_in[2];
  const float* conv3d_w         = (const float*)d_in[3];
  const float* conv3d_b         = (const float*)d_in[4];
  const float* ln_img_g         = (const float*)d_in[5];
  const float* ln_img_b         = (const float*)d_in[6];
  const float* ln_ins_g         = (const float*)d_in[7];
  const float* ln_ins_b         = (const float*)d_in[8];
  const float* ins_w            = (const float*)d_in[9];
  const float* ins_b            = (const float*)d_in[10];
  const float* img_w            = (const float*)d_in[11];
  const float* img_b            = (const float*)d_in[12];
  const float* head_w           = (const float*)d_in[13];
  const float* head_b           = (const float*)d_in[14];
  const float* in_proj_w        = (const float*)d_in[15];
  const float* norm_w           = (const float*)d_in[16];
  const float* conv_w           = (const float*)d_in[17];
  const float* conv_b           = (const float*)d_in[18];
  const float* dt_bias          = (const float*)d_in[19];
  const float* A_log            = (const float*)d_in[20];
  const float* Dp               = (const float*)d_in[21];
  const float* gnorm_w          = (const float*)d_in[22];
  const float* out_proj_w       = (const float*)d_in[23];
  const float* normf_w          = (const float*)d_in[24];

  // ---- workspace layout (floats) ----
  float* ws      = (float*)d_ws;
  float* h       = ws;                         // 786432
  float* mean    = h + 1024 * HID;             // 896
  float* rstd    = mean + CONV_ROWS;           // 896
  float* scratch = rstd + CONV_ROWS;

  const size_t ws_floats   = ws_size / sizeof(float);
  const size_t fixed       = (size_t)(scratch - ws);
  const size_t avail       = (ws_floats > fixed) ? (ws_floats - fixed) : 0;

  // stage-A chunk: largest multiple-of-64 row count whose conv buffer fits.
  int chunkM = (int)(avail / INPUT_DIM);
  chunkM = (chunkM / 64) * 64;
  if (chunkM > CONV_ROWS) chunkM = CONV_ROWS;
  if (chunkM < 64) chunkM = 64;

  float* conv_buf = scratch;                   // chunkM * 37632 floats

  // mamba-loop scratch aliases the (dead) conv buffer region
  float* hn    = scratch;                      // 786432
  float* proj  = hn + 1024 * HID;              // 3301376
  float* xbc   = proj + 1024 * PROJ_D;         // 1703936
  float* dtB   = xbc + 1024 * CONV_DIM;        // 24576
  float* dAB   = dtB + 1024 * NH;              // 24576
  float* yfull = dAB + 1024 * NH;              // 1572864
  float* yg    = yfull + 1024 * INTER;         // 1572864

  // ---- stage A: vision + instruction embedding ----
  k_hinit<<<(B_SZ * SIMG * HID + 255) / 256, 256, 0, stream>>>(img_b, h);
  k_ins<<<128, 256, 0, stream>>>(instruction_embs, ln_ins_g, ln_ins_b, ins_w, ins_b, h);

  for (int row0 = 0; row0 < CONV_ROWS; row0 += chunkM) {
    int m = CONV_ROWS - row0; if (m > chunkM) m = chunkM;   // multiple of 64
    k_conv3d<<<dim3(12, m), 256, 0, stream>>>(image_embs, conv3d_w, conv3d_b, conv_buf, row0);
    k_ln_stats<<<m, 256, 0, stream>>>(conv_buf, mean, rstd, row0);
    k_img_gemm<<<dim3(12, m / 64, 12), 256, 0, stream>>>(conv_buf, mean, rstd, ln_img_g,
                                                         ln_img_b, img_w, h, row0);
  }

  // ---- stage B: 4 mamba2 blocks ----
  for (int l = 0; l < NBLOCKS; ++l) {
    k_rmsnorm_mask<<<1024, 256, 0, stream>>>(h, norm_w + l * HID, pad_mask, hn);
    k_gemm64<false><<<dim3((PROJ_D + 63) / 64, 16), 256, 0, stream>>>(
        hn, in_proj_w + (size_t)l * HID * PROJ_D, proj, PROJ_D, HID);
    k_dconv<<<dim3((CONV_DIM + 255) / 256, LSEQ, B_SZ), 256, 0, stream>>>(
        proj, conv_w + l * CONV_DIM * KCONV, conv_b + l * CONV_DIM, pad_mask, xbc);
    k_dt<<<(B_SZ * LSEQ * NH + 255) / 256, 256, 0, stream>>>(
        proj, dt_bias + l * NH, A_log + l * NH, dtB, dAB);
    k_scan<<<dim3(NH, B_SZ), 256, 0, stream>>>(xbc, dtB, dAB, Dp + l * NH, yfull);
    k_gate<<<1024, 256, 0, stream>>>(yfull, proj, gnorm_w + l * INTER, yg);
    k_gemm64<true><<<dim3(HID / 64, 16), 256, 0, stream>>>(
        yg, out_proj_w + (size_t)l * INTER * HID, h, HID, INTER);
  }

  // ---- stage C: head ----
  k_head<<<dim3(SIMG, B_SZ), 256, 0, stream>>>(h, normf_w, head_w, head_b, (float*)d_out);
}